// Round 5
// baseline (188.441 us; speedup 1.0000x reference)
//
#include <hip/hip_runtime.h>

typedef _Float16 half2_t __attribute__((ext_vector_type(2)));

#define NBATCH 64
#define HDIM   128
#define NSTEP  64
#define NIN    16
#define HISTP  132   // hist stride in floats: 16B-aligned, breaks pow2 banks

__device__ __forceinline__ float sigf(float x) { return 1.f / (1.f + __expf(-x)); }

__device__ __forceinline__ unsigned int h2u(half2_t h) {
    union { half2_t h; unsigned int u; } x; x.h = h; return x.u;
}
__device__ __forceinline__ half2_t u2h(unsigned int u) {
    union { half2_t h; unsigned int u; } x; x.u = u; return x.h;
}

__global__ __launch_bounds__(256) void copy_trip_k(const float4* __restrict__ src,
                                                   float4* __restrict__ dst) {
    int i = blockIdx.x * 256 + threadIdx.x;   // 65536 float4 total
    dst[i] = src[i];
}

// Store packed W word into hard AGPR aK (survives the whole kernel; RA can't spill it)
#define PUTW(K) { \
    float w0_ = Wg[(base + 2*(K)) * 512 + j]; \
    float w1_ = Wg[(base + 2*(K) + 1) * 512 + j]; \
    half2_t hp_ = { (_Float16)w0_, (_Float16)w1_ }; \
    unsigned int u_ = h2u(hp_); \
    asm volatile("v_accvgpr_write_b32 a" #K ", %0" :: "v"(u_) : "a" #K); }

// One q-step: broadcast state words 2(lbase+Q), 2(lbase+Q)+1 via readlane,
// fetch W packs from AGPRs K0=2Q, K1=2Q+1, two f16 dot2 into 2 chains.
#define SQ(Q, K0, K1) { \
    unsigned int sx_ = (unsigned int)__builtin_amdgcn_readlane((int)vx, lbase + (Q)); \
    unsigned int sy_ = (unsigned int)__builtin_amdgcn_readlane((int)vy, lbase + (Q)); \
    unsigned int wa_, wb_; \
    asm volatile("v_accvgpr_read_b32 %0, a" #K0 : "=v"(wa_)); \
    asm volatile("v_accvgpr_read_b32 %0, a" #K1 : "=v"(wb_)); \
    acc0 = __builtin_amdgcn_fdot2(u2h(sx_), u2h(wa_), acc0, false); \
    acc1 = __builtin_amdgcn_fdot2(u2h(sy_), u2h(wb_), acc1, false); }

// 64 blocks (1/batch) x 1024 threads. Thread t: gate column j = t&511,
// K-half kh = t>>9. W fragment (64 packed f16 pairs) lives in AGPRs a0..a63.
__global__ __launch_bounds__(1024) void recur_k(
    const float* __restrict__ emb, const float* __restrict__ Wg,
    const float* __restrict__ bg,  const float* __restrict__ Wl,
    const float* __restrict__ bl,  float* __restrict__ proj_ws) {
    __shared__ __align__(16) unsigned int pack_s[128]; // f16 state [c(64w)|h(64w)]
    __shared__ float gpart[2][512];         // per-K-half partial gate sums
    __shared__ float hist[NSTEP * HISTP];   // c_s history (f32), 33.8 KB
    __shared__ float Wl_s[HDIM * NIN];      // 8 KB
    __shared__ float bg_s[512];

    const int b = blockIdx.x, t = threadIdx.x;
    const int j = t & 511, kh = t >> 9;
    const int lane = t & 63;
    const int lbase = kh << 5;              // wave-uniform: lanes 0..31 or 32..63
    const int base = kh * 128;              // W row base for this K-half

    // ---- W fragment -> AGPRs (one-time; coalesced row reads, L2/L3-hot) ----
    PUTW(0)  PUTW(1)  PUTW(2)  PUTW(3)  PUTW(4)  PUTW(5)  PUTW(6)  PUTW(7)
    PUTW(8)  PUTW(9)  PUTW(10) PUTW(11) PUTW(12) PUTW(13) PUTW(14) PUTW(15)
    PUTW(16) PUTW(17) PUTW(18) PUTW(19) PUTW(20) PUTW(21) PUTW(22) PUTW(23)
    PUTW(24) PUTW(25) PUTW(26) PUTW(27) PUTW(28) PUTW(29) PUTW(30) PUTW(31)
    PUTW(32) PUTW(33) PUTW(34) PUTW(35) PUTW(36) PUTW(37) PUTW(38) PUTW(39)
    PUTW(40) PUTW(41) PUTW(42) PUTW(43) PUTW(44) PUTW(45) PUTW(46) PUTW(47)
    PUTW(48) PUTW(49) PUTW(50) PUTW(51) PUTW(52) PUTW(53) PUTW(54) PUTW(55)
    PUTW(56) PUTW(57) PUTW(58) PUTW(59) PUTW(60) PUTW(61) PUTW(62) PUTW(63)

    if (t < 512) bg_s[t] = bg[t];
    for (int i = t; i < HDIM * NIN; i += 1024) Wl_s[i] = Wl[i];
    if (t < 64) {
        float e0 = emb[b * (64 * HDIM) + 2 * t + 0];
        float e1 = emb[b * (64 * HDIM) + 2 * t + 1];
        half2_t hp = { (_Float16)e0, (_Float16)e1 };
        pack_s[t] = h2u(hp);                // c-slot <- embedding row 0
    } else if (t < 128) {
        pack_s[t] = 0u;                     // h0 = 0
    }
    float c_reg = 0.f;                      // threads 0..127 own c[t]; c0 = 0
    __syncthreads();

    for (int s = 0; s < NSTEP; ++s) {
        // ---- whole 512B state into the wave: lane l <- words 2l, 2l+1 ----
        uint2 sv = *(const uint2*)((const char*)pack_s + lane * 8);
        unsigned int vx = sv.x, vy = sv.y;

        float acc0 = 0.f, acc1 = 0.f;
        SQ(0,0,1)    SQ(1,2,3)    SQ(2,4,5)    SQ(3,6,7)
        SQ(4,8,9)    SQ(5,10,11)  SQ(6,12,13)  SQ(7,14,15)
        SQ(8,16,17)  SQ(9,18,19)  SQ(10,20,21) SQ(11,22,23)
        SQ(12,24,25) SQ(13,26,27) SQ(14,28,29) SQ(15,30,31)
        SQ(16,32,33) SQ(17,34,35) SQ(18,36,37) SQ(19,38,39)
        SQ(20,40,41) SQ(21,42,43) SQ(22,44,45) SQ(23,46,47)
        SQ(24,48,49) SQ(25,50,51) SQ(26,52,53) SQ(27,54,55)
        SQ(28,56,57) SQ(29,58,59) SQ(30,60,61) SQ(31,62,63)
        gpart[kh][j] = acc0 + acc1;
        __syncthreads();

        // ---- state update: threads 0..127 own h index t ----
        if (t < HDIM) {
            float fg = sigf(gpart[0][t]       + gpart[1][t]       + bg_s[t]);
            float ig = sigf(gpart[0][128 + t] + gpart[1][128 + t] + bg_s[128 + t]);
            float og = sigf(gpart[0][256 + t] + gpart[1][256 + t] + bg_s[256 + t]);
            float cd = tanhf(gpart[0][384 + t] + gpart[1][384 + t] + bg_s[384 + t]);
            float c_new = fg * c_reg + ig * cd;
            float h_new = og * tanhf(c_new);
            c_reg = c_new;
            hist[s * HISTP + t] = c_new;
            float c_o = __shfl_xor(c_new, 1);
            float h_o = __shfl_xor(h_new, 1);
            if ((t & 1) == 0) {
                half2_t cp = { (_Float16)c_new, (_Float16)c_o };
                half2_t hp = { (_Float16)h_new, (_Float16)h_o };
                pack_s[(t >> 1)]      = h2u(cp);
                pack_s[64 + (t >> 1)] = h2u(hp);
            }
        }
        __syncthreads();
    }

    // ---- projection: thread t -> (s = t>>4, i = t&15); 256KB to ws ----
    {
        int s = t >> 4, i = t & 15;
        float acc = bl[i];
        const float4* c4 = (const float4*)&hist[s * HISTP];
        #pragma unroll 8
        for (int h4 = 0; h4 < HDIM / 4; ++h4) {
            float4 cv = c4[h4];
            int h = h4 * 4;
            acc = fmaf(cv.x, Wl_s[(h + 0) * NIN + i], acc);
            acc = fmaf(cv.y, Wl_s[(h + 1) * NIN + i], acc);
            acc = fmaf(cv.z, Wl_s[(h + 2) * NIN + i], acc);
            acc = fmaf(cv.w, Wl_s[(h + 3) * NIN + i], acc);
        }
        proj_ws[b * 1024 + t] = acc;   // [b][s][i]
    }
}

// 4096 blocks (b*64+s) x 256 threads: broadcast proj row to 64 output rows.
__global__ __launch_bounds__(256) void expand_k(const float* __restrict__ proj_ws,
                                                float* __restrict__ out) {
    int blk = blockIdx.x;             // b*64 + s
    int t = threadIdx.x;
    const float4* pj = (const float4*)(proj_ws + blk * 16);
    float4 v = pj[t & 3];             // broadcast 4 lines, L2-hot
    float4* ob = (float4*)(out + (size_t)blk * 1024);  // 64 rows x 16 f
    ob[t] = v;
}

extern "C" void kernel_launch(void* const* d_in, const int* in_sizes, int n_in,
                              void* d_out, int out_size, void* d_ws, size_t ws_size,
                              hipStream_t stream) {
    const float* trip = (const float*)d_in[0];
    // d_in[1] = valid_len : unused by the reference computation
    const float* emb  = (const float*)d_in[2];
    const float* Wg   = (const float*)d_in[3];
    const float* bgp  = (const float*)d_in[4];
    const float* Wlp  = (const float*)d_in[5];
    const float* blp  = (const float*)d_in[6];
    float* out = (float*)d_out;
    float* proj_ws = (float*)d_ws;    // 64*64*16 floats = 256 KB

    // output = [trip (262144 floats) | out (4194304 floats)]
    copy_trip_k<<<256, 256, 0, stream>>>((const float4*)trip, (float4*)out);
    recur_k<<<NBATCH, 1024, 0, stream>>>(emb, Wg, bgp, Wlp, blp, proj_ws);
    expand_k<<<NBATCH * NSTEP, 256, 0, stream>>>(proj_ws, out + 262144);
}

// Round 6
// 115.827 us; speedup vs baseline: 1.6269x; 1.6269x over previous
//
#include <hip/hip_runtime.h>

typedef _Float16 f16x8 __attribute__((ext_vector_type(8)));
typedef float f32x4 __attribute__((ext_vector_type(4)));

#define HDIM  128
#define NSTEP 64
#define NG    512   // 4H gate columns
#define BPB   16    // batches per block (MFMA M)

__device__ __forceinline__ float sigf(float x) {
    return __builtin_amdgcn_rcpf(1.f + __expf(-x));
}
__device__ __forceinline__ float tanhfast(float x) {
    return fmaf(2.f, __builtin_amdgcn_rcpf(1.f + __expf(-2.f * x)), -1.f);
}
__device__ __forceinline__ unsigned int packh2(float a, float b) {
    union { _Float16 h[2]; unsigned int u; } x;
    x.h[0] = (_Float16)a; x.h[1] = (_Float16)b; return x.u;
}

__global__ __launch_bounds__(256) void copy_trip_k(const float4* __restrict__ src,
                                                   float4* __restrict__ dst) {
    int i = blockIdx.x * 256 + threadIdx.x;   // 65536 float4 total
    dst[i] = src[i];
}

// grid = 4 blocks x 512 threads (8 waves). Block owns 16 batches.
// Wave w owns gate-column tiles nt = 4w..4w+3 (64 cols), all 8 k-tiles.
// W fragments (32 x f16x8 = 128 AGPRs) pinned resident; MFMA reads AGPR natively.
__global__ __launch_bounds__(512, 2) void recur_k(
    const float* __restrict__ emb, const float* __restrict__ Wg,
    const float* __restrict__ bg,  float* __restrict__ outb) {
    __shared__ __align__(16) unsigned short state_s[BPB * 256]; // f16 [c|h] per batch, XOR-swizzled, 8 KB
    __shared__ float g_s[BPB * NG];                             // gates f32, 32 KB

    const int blk = blockIdx.x, t = threadIdx.x;
    const int w = t >> 6, l = t & 63;
    const int lg = l >> 4, lr = l & 15;     // k-group, dim-row within group

    // ---- B-fragments + bias (one-time). k-map: k = kt*32 + lg*8 + e (same map
    // used for A below; MFMA dot is invariant under a common k-permutation). ----
    f16x8 B[4][8];
    float bgc[4];
    #pragma unroll
    for (int i = 0; i < 4; ++i) {
        const int c = (w * 4 + i) * 16 + lr;
        bgc[i] = bg[c];
        #pragma unroll
        for (int kt = 0; kt < 8; ++kt) {
            f16x8 v;
            #pragma unroll
            for (int e = 0; e < 8; ++e)
                v[e] = (_Float16)Wg[(kt * 32 + lg * 8 + e) * NG + c];
            B[i][kt] = v;
        }
    }
    #pragma unroll
    for (int i = 0; i < 4; ++i)
        #pragma unroll
        for (int kt = 0; kt < 8; ++kt)
            asm volatile("" : "+a"(B[i][kt]));   // pin W into AGPR class, not rematerializable

    // ---- initial state: [c=emb_row0 | h=0] as f16, XOR-swizzled rows ----
    for (int wd = t; wd < BPB * 128; wd += 512) {
        int batch = wd >> 7, kw = wd & 127;      // 4-byte word = halves k=2kw,2kw+1
        unsigned int val = 0u;
        if (kw < 64) {
            const float* e2 = emb + (size_t)(blk * BPB + batch) * 64 * HDIM + 2 * kw;
            val = packh2(e2[0], e2[1]);
        }
        *(unsigned int*)((char*)state_s + batch * 512 + ((kw * 4) ^ ((batch & 7) << 4))) = val;
    }

    const int batA = t >> 6;   // wave handles batches batA and batA+8 in update
    const int pp = t & 63;     // h-pair index: h = 2*pp, 2*pp+1
    float c0a = 0.f, c1a = 0.f, c0b = 0.f, c1b = 0.f;   // c state lives here (c0 = 0)
    __syncthreads();

    #define LD2(bb, off) (*(const float2*)&g_s[(bb) * NG + ((((off) + 2 * pp)) ^ (((bb) & 1) << 4))])

    for (int s = 0; s < NSTEP; ++s) {
        // ---- MFMA phase: g[16,512] = state[16,256] @ W + bias ----
        f32x4 acc[4];
        #pragma unroll
        for (int i = 0; i < 4; ++i) acc[i] = (f32x4){bgc[i], bgc[i], bgc[i], bgc[i]};
        #pragma unroll
        for (int kt = 0; kt < 8; ++kt) {
            const int byte = lr * 512 + ((kt * 64 + lg * 16) ^ ((lr & 7) << 4));
            f16x8 a8 = *(const f16x8*)((const char*)state_s + byte);
            #pragma unroll
            for (int i = 0; i < 4; ++i)
                acc[i] = __builtin_amdgcn_mfma_f32_16x16x32_f16(a8, B[i][kt], acc[i], 0, 0, 0);
        }
        // D layout (m89): row(batch) = lg*4+q, col = lr (+ tile*16)
        #pragma unroll
        for (int i = 0; i < 4; ++i) {
            const int col = (w * 4 + i) * 16 + lr;
            #pragma unroll
            for (int q = 0; q < 4; ++q) {
                const int batch = lg * 4 + q;
                g_s[batch * NG + (col ^ ((batch & 1) << 4))] = acc[i][q];
            }
        }
        __syncthreads();

        // ---- update phase: thread -> (batA, pp) and (batA+8, pp) ----
        {
            const int bb = batA;
            float2 gF = LD2(bb, 0), gI = LD2(bb, 128), gO = LD2(bb, 256), gC = LD2(bb, 384);
            float F0 = sigf(gF.x), F1 = sigf(gF.y);
            float I0 = sigf(gI.x), I1 = sigf(gI.y);
            float O0 = sigf(gO.x), O1 = sigf(gO.y);
            float D0 = tanhfast(gC.x), D1 = tanhfast(gC.y);
            float cn0 = fmaf(F0, c0a, I0 * D0);
            float cn1 = fmaf(F1, c1a, I1 * D1);
            float hn0 = O0 * tanhfast(cn0), hn1 = O1 * tanhfast(cn1);
            c0a = cn0; c1a = cn1;
            *(unsigned int*)((char*)state_s + bb * 512 + ((pp * 4) ^ ((bb & 7) << 4))) = packh2(cn0, cn1);
            *(unsigned int*)((char*)state_s + bb * 512 + ((256 + pp * 4) ^ ((bb & 7) << 4))) = packh2(hn0, hn1);
            *(float2*)(outb + (size_t)(blk * BPB + bb) * 65536 + s * 1024 + 2 * pp) = make_float2(cn0, cn1);
        }
        {
            const int bb = batA + 8;
            float2 gF = LD2(bb, 0), gI = LD2(bb, 128), gO = LD2(bb, 256), gC = LD2(bb, 384);
            float F0 = sigf(gF.x), F1 = sigf(gF.y);
            float I0 = sigf(gI.x), I1 = sigf(gI.y);
            float O0 = sigf(gO.x), O1 = sigf(gO.y);
            float D0 = tanhfast(gC.x), D1 = tanhfast(gC.y);
            float cn0 = fmaf(F0, c0b, I0 * D0);
            float cn1 = fmaf(F1, c1b, I1 * D1);
            float hn0 = O0 * tanhfast(cn0), hn1 = O1 * tanhfast(cn1);
            c0b = cn0; c1b = cn1;
            *(unsigned int*)((char*)state_s + bb * 512 + ((pp * 4) ^ ((bb & 7) << 4))) = packh2(cn0, cn1);
            *(unsigned int*)((char*)state_s + bb * 512 + ((256 + pp * 4) ^ ((bb & 7) << 4))) = packh2(hn0, hn1);
            *(float2*)(outb + (size_t)(blk * BPB + bb) * 65536 + s * 1024 + 2 * pp) = make_float2(cn0, cn1);
        }
        __syncthreads();
    }
}

// 4096 blocks (b*64+s) x 256 threads. recur stashed c[b][s][0:128] in the first
// 512 B of this block's OWN 4 KB output region; read it (to LDS), then overwrite
// the region with the projected row replicated 64x. No cross-block hazard.
__global__ __launch_bounds__(256) void proj_expand_k(const float* __restrict__ Wl,
                                                     const float* __restrict__ bl,
                                                     float* __restrict__ outb) {
    __shared__ float c_s[HDIM];
    __shared__ __align__(16) float pj[16];
    const int bs = blockIdx.x, t = threadIdx.x;
    float* reg = outb + (size_t)bs * 1024;
    if (t < HDIM) c_s[t] = reg[t];
    __syncthreads();
    if (t < 16) {
        float a = bl[t];
        #pragma unroll 16
        for (int h = 0; h < HDIM; ++h) a = fmaf(c_s[h], Wl[h * 16 + t], a);
        pj[t] = a;
    }
    __syncthreads();
    float4 v = ((const float4*)pj)[t & 3];
    ((float4*)reg)[t] = v;   // 256 float4 = 64 rows x 16 floats
}

extern "C" void kernel_launch(void* const* d_in, const int* in_sizes, int n_in,
                              void* d_out, int out_size, void* d_ws, size_t ws_size,
                              hipStream_t stream) {
    const float* trip = (const float*)d_in[0];
    // d_in[1] = valid_len : unused by the reference computation
    const float* emb  = (const float*)d_in[2];
    const float* Wg   = (const float*)d_in[3];
    const float* bgp  = (const float*)d_in[4];
    const float* Wlp  = (const float*)d_in[5];
    const float* blp  = (const float*)d_in[6];
    float* out = (float*)d_out;

    // output = [trip (262144 floats) | big (4194304 floats)]
    copy_trip_k<<<256, 256, 0, stream>>>((const float4*)trip, (float4*)out);
    recur_k<<<4, 512, 0, stream>>>(emb, Wg, bgp, out + 262144);
    proj_expand_k<<<4096, 256, 0, stream>>>(Wlp, blp, out + 262144);
}